// Round 13
// baseline (239.096 us; speedup 1.0000x reference)
//
#include <hip/hip_runtime.h>
#include <hip/hip_bf16.h>
#include <stdint.h>

// MultiHeadSelfAttention: B=2,C=256,H=8,P=32,X=Y=Z=48
// Model: DRAM-segment-bound staging (384B runs) + phase-overlap via >=2
// blocks/CU. K1: 1024thr/16 waves, single-pass GEMM acc[2][6] (R12-proven,
// no spill), qkz reuses xT region in two z-halves -> LDS 57344 (2 blocks/CU).
//
// HARD RULES (spill tripwire: WRITE_SIZE >> expected output bytes):
//  - Per-wave GEMM acc shape acc[2][6] max; NO runtime loop around acc phases
//    (R10 unroll 285MB / R11 unroll-1 687MB scratch). Straight-line halves only.
//  - launch_bounds waves-per-EU stays 4 (R4/R6: higher -> 64-reg cap -> spill).
//  - staging: R8 scalar-dword granule ONLY (R9 float4: neutral + replay-race).
//  - 1 block/CU serializes stage/compute (R12: k_qk 133us); need >=2 blocks.

#define S_TOT 110592   // 48*48*48
#define NBX   2304     // (x,y) columns

typedef unsigned short u16;
typedef __attribute__((ext_vector_type(8))) short bf16x8;
typedef __attribute__((ext_vector_type(4))) float f32x4;

__device__ __forceinline__ u16 f2b(float f){
  union { float f; uint32_t u; } v; v.f = f;
  uint32_t u = v.u;
  return (u16)((u + 0x7fffu + ((u >> 16) & 1u)) >> 16);   // RNE
}
__device__ __forceinline__ float b2f(u16 h){
  union { float f; uint32_t u; } v; v.u = ((uint32_t)h) << 16; return v.f;
}
__device__ __forceinline__ f32x4 mfma16(bf16x8 a, bf16x8 b, f32x4 c){
  return __builtin_amdgcn_mfma_f32_16x16x32_bf16(a, b, c, 0, 0, 0);
}

// ---------------- K0: weight prep -> tight bf16 images -----------------------
__global__ __launch_bounds__(256) void k_prep(
    const float* __restrict__ wq, const float* __restrict__ wk,
    const float* __restrict__ wv, const float* __restrict__ wo,
    u16* __restrict__ img)
{
  int idx = blockIdx.x * 256 + threadIdx.x;
  if (idx < 131072){
    int ck = idx >> 14, rem = idx & 16383;
    int r = rem >> 5, i = rem & 31;
    int c = ck * 32 + i;
    float v = (r < 256) ? wq[r * 256 + c] : wk[(r - 256) * 256 + c];
    img[idx] = f2b(v);
  } else if (idx < 196608){
    int l = idx - 131072;
    int ck = l >> 13, rem = l & 8191;
    int r = rem >> 5, i = rem & 31;
    img[idx] = f2b(wv[r * 256 + ck * 32 + i]);
  } else if (idx < 262144){
    int l = idx - 196608;
    int ck = l >> 13, rem = l & 8191;
    int r = rem >> 5, i = rem & 31;
    img[idx] = f2b(wo[r * 256 + ck * 32 + i]);
  }
}

// ---------------- K1: 96-spatial q,k proj + scores, 1024 thr / 16 waves ------
// Phase A: xT [96][256] @0 (49152), single-pass GEMM acc[2][6] per wave.
// Phase B (xT dead): qkz [48 local z][512 ch] @0 reuses region; two straight-
// line z-halves (col 0: z 0-47, col 1: z 48-95), score via MFMA (K=p).
// LDS: 49152 + ps0 4096 + ps1 4096 = 57344 -> 2 blocks/CU (wave-capped).
#define K1_LDS 57344
__global__ __launch_bounds__(1024, 4) void k_qk_scores(
    const float* __restrict__ x, const u16* __restrict__ wimg,
    const float* __restrict__ bq, const float* __restrict__ bk,
    float* __restrict__ scores)
{
  extern __shared__ char lds[];
  u16* xT  = (u16*)lds;                     // [96][256], pitch 512 B
  u16* qkz = (u16*)lds;                     // [48][512], pitch 1024 B (reuse)
  float* ps0 = (float*)(lds + 49152);       // [16][64]
  float* ps1 = (float*)(lds + 53248);       // [16][64]

  const int tid  = threadIdx.x;
  const int wave = tid >> 6, lane = tid & 63;
  const int l15 = lane & 15, l4 = lane >> 4;
  const int bx = blockIdx.x, b = blockIdx.y;   // bx: 0..1151 (y-pair)
  const int s0 = bx * 96;
  const float* xb = x + (size_t)b * 256 * S_TOT;

  // stage x -> xT (R8 scalar-granule form; 384 B DRAM runs per channel)
  #pragma unroll
  for (int it = 0; it < 3; it++){
    int e = it * 1024 + tid;
    int z = e % 96, c16 = e / 96;
    const float* px = xb + (size_t)(c16 * 8) * S_TOT + s0 + z;
    union { uint4 q; u16 h[8]; } u;
    #pragma unroll
    for (int i = 0; i < 8; i++) u.h[i] = f2b(px[(size_t)i * S_TOT]);
    *(uint4*)((char*)xT + z * 512 + ((c16 ^ (z & 7)) << 4)) = u.q;
  }
  __syncthreads();

  const int proj = wave >> 3;            // 0=q (waves 0-7), 1=k (waves 8-15)
  const int rb = (wave & 7) * 32;        // row base within proj
  const float* bias = proj ? bk : bq;

  // ---- q,k GEMM: wave owns 32 rows x 96 cols (acc[2][6], proven shape)
  f32x4 acc[2][6];
  #pragma unroll
  for (int fr = 0; fr < 2; fr++){
    f32x4 iv;
    #pragma unroll
    for (int j = 0; j < 4; j++) iv[j] = bias[rb + fr * 16 + l4 * 4 + j];
    #pragma unroll
    for (int fc = 0; fc < 6; fc++) acc[fr][fc] = iv;
  }
  #pragma unroll
  for (int ck = 0; ck < 8; ck++){
    bf16x8 af[2], bfr[6];
    #pragma unroll
    for (int fr = 0; fr < 2; fr++){
      int row = wave * 32 + fr * 16 + l15;       // row within 512 (q|k)
      af[fr] = *(const bf16x8*)(wimg + ck * 16384 + row * 32 + l4 * 8);
    }
    #pragma unroll
    for (int fc = 0; fc < 6; fc++){
      int z = fc * 16 + l15;
      bfr[fc] = *(const bf16x8*)((char*)xT + z * 512 + (((ck * 4 + l4) ^ (l15 & 7)) << 4));
    }
    #pragma unroll
    for (int fr = 0; fr < 2; fr++)
      #pragma unroll
      for (int fc = 0; fc < 6; fc++)
        acc[fr][fc] = mfma16(af[fr], bfr[fc], acc[fr][fc]);
  }
  __syncthreads();   // ALL waves done reading xT; region reusable as qkz

  const int och = proj * 256 + rb + l4 * 4;          // + fr*16
  const int ca = l15 * 32 + l4 * 8;                  // q channels (rows 8-15 junk)
  const int cb = 256 + (l15 & 7) * 32 + l4 * 8;      // k channels (dup col>=8)

  // ======== half 0: column bx*2 (global z 0..47) ========
  #pragma unroll
  for (int fr = 0; fr < 2; fr++){
    int oc = och + fr * 16;
    #pragma unroll
    for (int fc = 0; fc < 3; fc++){
      int zl = fc * 16 + l15;
      ushort4 u;
      u.x = f2b(acc[fr][fc][0]); u.y = f2b(acc[fr][fc][1]);
      u.z = f2b(acc[fr][fc][2]); u.w = f2b(acc[fr][fc][3]);
      *(ushort4*)((char*)qkz + zl * 1024 + ((((oc >> 3) ^ zl) & 63) << 4)
                  + (oc & 7) * 2) = u;
    }
  }
  __syncthreads();
  {
    f32x4 sc = {0.f, 0.f, 0.f, 0.f};
    #pragma unroll
    for (int zi = 0; zi < 3; zi++){
      int zl = wave * 3 + zi;
      bf16x8 aq  = *(const bf16x8*)((char*)qkz + zl * 1024 + ((((ca >> 3) ^ zl) & 63) << 4));
      bf16x8 bk8 = *(const bf16x8*)((char*)qkz + zl * 1024 + ((((cb >> 3) ^ zl) & 63) << 4));
      sc = mfma16(aq, bk8, sc);
    }
    if (l4 < 2 && l15 < 8){
      #pragma unroll
      for (int j = 0; j < 4; j++)
        ps0[wave * 64 + (l4 * 4 + j) * 8 + l15] = sc[j];
    }
  }
  __syncthreads();

  // reduce col 0 (reads ps0) runs alongside half-1 epilogue (writes qkz)
  if (tid < 64){
    float s = 0.f;
    #pragma unroll
    for (int w = 0; w < 16; w++) s += ps0[w * 64 + tid];
    scores[(size_t)(b * 64 + tid) * NBX + bx * 2] = s * 0.17677669529663687f;
  }
  // ======== half 1: column bx*2+1 (global z 48..95) ========
  #pragma unroll
  for (int fr = 0; fr < 2; fr++){
    int oc = och + fr * 16;
    #pragma unroll
    for (int fc = 3; fc < 6; fc++){
      int zl = (fc - 3) * 16 + l15;
      ushort4 u;
      u.x = f2b(acc[fr][fc][0]); u.y = f2b(acc[fr][fc][1]);
      u.z = f2b(acc[fr][fc][2]); u.w = f2b(acc[fr][fc][3]);
      *(ushort4*)((char*)qkz + zl * 1024 + ((((oc >> 3) ^ zl) & 63) << 4)
                  + (oc & 7) * 2) = u;
    }
  }
  __syncthreads();
  {
    f32x4 sc = {0.f, 0.f, 0.f, 0.f};
    #pragma unroll
    for (int zi = 0; zi < 3; zi++){
      int zl = wave * 3 + zi;
      bf16x8 aq  = *(const bf16x8*)((char*)qkz + zl * 1024 + ((((ca >> 3) ^ zl) & 63) << 4));
      bf16x8 bk8 = *(const bf16x8*)((char*)qkz + zl * 1024 + ((((cb >> 3) ^ zl) & 63) << 4));
      sc = mfma16(aq, bk8, sc);
    }
    if (l4 < 2 && l15 < 8){
      #pragma unroll
      for (int j = 0; j < 4; j++)
        ps1[wave * 64 + (l4 * 4 + j) * 8 + l15] = sc[j];
    }
  }
  __syncthreads();
  if (tid < 64){
    float s = 0.f;
    #pragma unroll
    for (int w = 0; w < 16; w++) s += ps1[w * 64 + tid];
    scores[(size_t)(b * 64 + tid) * NBX + bx * 2 + 1] = s * 0.17677669529663687f;
  }
}

// ---------------- K2: softmax over y ------------------------------------------
__global__ __launch_bounds__(256) void k_softmax(
    const float* __restrict__ scores, float* __restrict__ attn)
{
  int row  = blockIdx.x * 4 + (threadIdx.x >> 6);
  int lane = threadIdx.x & 63;
  const float* src = scores + (size_t)row * 48;
  float v = (lane < 48) ? src[lane] : -1e30f;
  float m = v;
  #pragma unroll
  for (int off = 32; off; off >>= 1) m = fmaxf(m, __shfl_xor(m, off));
  float e = (lane < 48) ? __expf(v - m) : 0.f;
  float s = e;
  #pragma unroll
  for (int off = 32; off; off >>= 1) s += __shfl_xor(s, off);
  if (lane < 48) attn[(size_t)row * 48 + lane] = e / s;
}

// ---------------- K3: 96-spatial (y-pair): v proj + attn*v + wo GEMM ---------
// (byte-identical to R8/R12 — replay-proven)
#define K3_LDS 49664
__global__ __launch_bounds__(512, 4) void k_out(
    const float* __restrict__ x, const u16* __restrict__ wvimg,
    const u16* __restrict__ woimg, const float* __restrict__ bv,
    const float* __restrict__ bo, const float* __restrict__ attn,
    float* __restrict__ out)
{
  extern __shared__ char lds[];
  u16* xT = (u16*)lds;
  u16* vl = (u16*)lds;
  u16* oT = (u16*)lds;
  float* atl = (float*)(lds + 49152);

  const int tid  = threadIdx.x;
  const int wave = tid >> 6, lane = tid & 63;
  const int l15 = lane & 15, l4 = lane >> 4;
  const int bx = blockIdx.x, b = blockIdx.y;   // bx: 0..1151 (y-pair)
  const int s0 = bx * 96;
  const float* xb = x + (size_t)b * 256 * S_TOT;

  if (tid < 128)
    atl[tid] = attn[(size_t)(b * 64 + (tid & 63)) * NBX + bx * 2 + (tid >> 6)];

  // stage x -> xT [96 z][256 ch] (R8 scalar-granule form)
  #pragma unroll
  for (int it = 0; it < 6; it++){
    int e = it * 512 + tid;
    int z = e % 96, c16 = e / 96;
    const float* px = xb + (size_t)(c16 * 8) * S_TOT + s0 + z;
    union { uint4 q; u16 h[8]; } u;
    #pragma unroll
    for (int i = 0; i < 8; i++) u.h[i] = f2b(px[(size_t)i * S_TOT]);
    *(uint4*)((char*)xT + z * 512 + ((c16 ^ (z & 7)) << 4)) = u.q;
  }
  __syncthreads();

  // ---- v GEMM: wave owns channels wave*32..+31, 96 spatial cols
  f32x4 vac[2][6];
  #pragma unroll
  for (int fr = 0; fr < 2; fr++){
    f32x4 iv;
    #pragma unroll
    for (int j = 0; j < 4; j++) iv[j] = bv[wave * 32 + fr * 16 + l4 * 4 + j];
    #pragma unroll
    for (int fc = 0; fc < 6; fc++) vac[fr][fc] = iv;
  }
  #pragma unroll
  for (int ck = 0; ck < 8; ck++){
    bf16x8 af[2], bfr[6];
    #pragma unroll
    for (int fr = 0; fr < 2; fr++){
      int row = wave * 32 + fr * 16 + l15;
      af[fr] = *(const bf16x8*)(wvimg + ck * 8192 + row * 32 + l4 * 8);
    }
    #pragma unroll
    for (int fc = 0; fc < 6; fc++){
      int z = fc * 16 + l15;
      bfr[fc] = *(const bf16x8*)((char*)xT + z * 512 + (((ck * 4 + l4) ^ (l15 & 7)) << 4));
    }
    #pragma unroll
    for (int fr = 0; fr < 2; fr++)
      #pragma unroll
      for (int fc = 0; fc < 6; fc++)
        vac[fr][fc] = mfma16(af[fr], bfr[fc], vac[fr][fc]);
  }
  __syncthreads();

  // ---- v epilogue -> vl (overwrites xT)
  #pragma unroll
  for (int fr = 0; fr < 2; fr++){
    int o0 = wave * 32 + fr * 16 + l4 * 4;
    #pragma unroll
    for (int fc = 0; fc < 6; fc++){
      int z = fc * 16 + l15;
      ushort4 u;
      u.x = f2b(vac[fr][fc][0]); u.y = f2b(vac[fr][fc][1]);
      u.z = f2b(vac[fr][fc][2]); u.w = f2b(vac[fr][fc][3]);
      *(ushort4*)((char*)vl + z * 512 + (((o0 >> 3) ^ (z & 7)) << 4) + (o0 & 7) * 2) = u;
    }
  }
  __syncthreads();

  // ---- einsum IN PLACE: it covers z rows [it*16, it*16+16)
  #pragma unroll
  for (int it = 0; it < 6; it++){
    int e = it * 512 + tid;
    int c16 = e & 31, z = e >> 5;
    int r = c16 & 3, hn = c16 >> 2;
    const float* at = atl + ((z >= 48) ? 64 : 0);
    float a[8] = {0,0,0,0,0,0,0,0};
    #pragma unroll
    for (int m = 0; m < 8; m++){
      union { uint4 q; u16 h[8]; } v8;
      v8.q = *(const uint4*)((char*)vl + z * 512 + (((m * 4 + r) ^ (z & 7)) << 4));
      float am = at[hn * 8 + m];
      #pragma unroll
      for (int i = 0; i < 8; i++) a[i] = fmaf(am, b2f(v8.h[i]), a[i]);
    }
    union { uint4 q; u16 h[8]; } pk;
    #pragma unroll
    for (int i = 0; i < 8; i++) pk.h[i] = f2b(a[i]);
    __syncthreads();
    *(uint4*)((char*)oT + z * 512 + ((c16 ^ (z & 7)) << 4)) = pk.q;
  }
  __syncthreads();

  // ---- wo GEMM (reads oT)
  f32x4 oac[2][6];
  #pragma unroll
  for (int fr = 0; fr < 2; fr++){
    f32x4 iv;
    #pragma unroll
    for (int j = 0; j < 4; j++) iv[j] = bo[wave * 32 + fr * 16 + l4 * 4 + j];
    #pragma unroll
    for (int fc = 0; fc < 6; fc++) oac[fr][fc] = iv;
  }
  #pragma unroll
  for (int ck = 0; ck < 8; ck++){
    bf16x8 af[2], bfr[6];
    #pragma unroll
    for (int fr = 0; fr < 2; fr++){
      int row = wave * 32 + fr * 16 + l15;
      af[fr] = *(const bf16x8*)(woimg + ck * 8192 + row * 32 + l4 * 8);
    }
    #pragma unroll
    for (int fc = 0; fc < 6; fc++){
      int z = fc * 16 + l15;
      bfr[fc] = *(const bf16x8*)((char*)oT + z * 512 + (((ck * 4 + l4) ^ (l15 & 7)) << 4));
    }
    #pragma unroll
    for (int fr = 0; fr < 2; fr++)
      #pragma unroll
      for (int fc = 0; fc < 6; fc++)
        oac[fr][fc] = mfma16(af[fr], bfr[fc], oac[fr][fc]);
  }

  // ---- store fp32: 384 B contiguous per channel
  #pragma unroll
  for (int fr = 0; fr < 2; fr++)
    #pragma unroll
    for (int fc = 0; fc < 6; fc++)
      #pragma unroll
      for (int j = 0; j < 4; j++){
        int o = wave * 32 + fr * 16 + l4 * 4 + j;
        int z = fc * 16 + l15;
        out[(size_t)(b * 256 + o) * S_TOT + s0 + z] = oac[fr][fc][j];
      }
}

// ---------------- launch ------------------------------------------------------
extern "C" void kernel_launch(void* const* d_in, const int* in_sizes, int n_in,
                              void* d_out, int out_size, void* d_ws, size_t ws_size,
                              hipStream_t stream) {
  (void)in_sizes; (void)n_in; (void)out_size; (void)ws_size;
  const float* x  = (const float*)d_in[0];
  const float* wq = (const float*)d_in[1];
  const float* bq = (const float*)d_in[2];
  const float* wk = (const float*)d_in[3];
  const float* bk = (const float*)d_in[4];
  const float* wv = (const float*)d_in[5];
  const float* bv = (const float*)d_in[6];
  const float* wo = (const float*)d_in[7];
  const float* bo = (const float*)d_in[8];
  float* out = (float*)d_out;

  char* ws = (char*)d_ws;
  u16*  wimg   = (u16*)ws;                    // 262144 u16 = 524288 B
  u16*  wvimg  = wimg + 131072;
  u16*  woimg  = wimg + 196608;
  float* scores = (float*)(ws + 524288);      // 128*2304*4 = 1179648 B
  float* attn   = (float*)(ws + 1703936);     // 1179648 B (end ~2.9 MB)

  k_prep<<<1024, 256, 0, stream>>>(wq, wk, wv, wo, wimg);
  k_qk_scores<<<dim3(1152, 2), 1024, K1_LDS, stream>>>(x, wimg, bq, bk, scores);
  k_softmax<<<1536, 256, 0, stream>>>(scores, attn);
  k_out<<<dim3(1152, 2), 512, K3_LDS, stream>>>(x, wvimg, woimg, bv, bo, attn, out);
}

// Round 14
// 219.268 us; speedup vs baseline: 1.0904x; 1.0904x over previous
//
#include <hip/hip_runtime.h>
#include <hip/hip_bf16.h>
#include <stdint.h>

// MultiHeadSelfAttention: B=2,C=256,H=8,P=32,X=Y=Z=48
// Model (R13): x (226MB) fits L3, but out's 226MB write stream evicts half of
// it each iteration -> k_qk re-fetches 113MB from HBM at page-limited ~1.2TB/s
// (384B segments @ 442KB stride). Fix: NON-TEMPORAL stores for out (write-once
// data) -> x stays L3-resident. Only change vs R13.
//
// HARD RULES (spill tripwire: WRITE_SIZE >> expected output bytes):
//  - Per-wave GEMM acc shape acc[2][6] max; NO runtime loop around acc phases
//    (R10/R11: 285-687MB scratch). Straight-line halves only.
//  - launch_bounds waves-per-EU stays 4 (R4/R6).
//  - staging: R8 scalar-dword granule ONLY (R9 float4: neutral + replay-race).
//  - occupancy/blocks-per-CU NOT a lever (R7, R13: zero change).

#define S_TOT 110592   // 48*48*48
#define NBX   2304     // (x,y) columns

typedef unsigned short u16;
typedef __attribute__((ext_vector_type(8))) short bf16x8;
typedef __attribute__((ext_vector_type(4))) float f32x4;

__device__ __forceinline__ u16 f2b(float f){
  union { float f; uint32_t u; } v; v.f = f;
  uint32_t u = v.u;
  return (u16)((u + 0x7fffu + ((u >> 16) & 1u)) >> 16);   // RNE
}
__device__ __forceinline__ float b2f(u16 h){
  union { float f; uint32_t u; } v; v.u = ((uint32_t)h) << 16; return v.f;
}
__device__ __forceinline__ f32x4 mfma16(bf16x8 a, bf16x8 b, f32x4 c){
  return __builtin_amdgcn_mfma_f32_16x16x32_bf16(a, b, c, 0, 0, 0);
}

// ---------------- K0: weight prep -> tight bf16 images -----------------------
__global__ __launch_bounds__(256) void k_prep(
    const float* __restrict__ wq, const float* __restrict__ wk,
    const float* __restrict__ wv, const float* __restrict__ wo,
    u16* __restrict__ img)
{
  int idx = blockIdx.x * 256 + threadIdx.x;
  if (idx < 131072){
    int ck = idx >> 14, rem = idx & 16383;
    int r = rem >> 5, i = rem & 31;
    int c = ck * 32 + i;
    float v = (r < 256) ? wq[r * 256 + c] : wk[(r - 256) * 256 + c];
    img[idx] = f2b(v);
  } else if (idx < 196608){
    int l = idx - 131072;
    int ck = l >> 13, rem = l & 8191;
    int r = rem >> 5, i = rem & 31;
    img[idx] = f2b(wv[r * 256 + ck * 32 + i]);
  } else if (idx < 262144){
    int l = idx - 196608;
    int ck = l >> 13, rem = l & 8191;
    int r = rem >> 5, i = rem & 31;
    img[idx] = f2b(wo[r * 256 + ck * 32 + i]);
  }
}

// ---------------- K1: 96-spatial q,k proj + scores, 1024 thr / 16 waves ------
// (byte-identical to R13)
#define K1_LDS 57344
__global__ __launch_bounds__(1024, 4) void k_qk_scores(
    const float* __restrict__ x, const u16* __restrict__ wimg,
    const float* __restrict__ bq, const float* __restrict__ bk,
    float* __restrict__ scores)
{
  extern __shared__ char lds[];
  u16* xT  = (u16*)lds;                     // [96][256], pitch 512 B
  u16* qkz = (u16*)lds;                     // [48][512], pitch 1024 B (reuse)
  float* ps0 = (float*)(lds + 49152);       // [16][64]
  float* ps1 = (float*)(lds + 53248);       // [16][64]

  const int tid  = threadIdx.x;
  const int wave = tid >> 6, lane = tid & 63;
  const int l15 = lane & 15, l4 = lane >> 4;
  const int bx = blockIdx.x, b = blockIdx.y;   // bx: 0..1151 (y-pair)
  const int s0 = bx * 96;
  const float* xb = x + (size_t)b * 256 * S_TOT;

  // stage x -> xT (R8 scalar-granule form; 384 B DRAM runs per channel)
  #pragma unroll
  for (int it = 0; it < 3; it++){
    int e = it * 1024 + tid;
    int z = e % 96, c16 = e / 96;
    const float* px = xb + (size_t)(c16 * 8) * S_TOT + s0 + z;
    union { uint4 q; u16 h[8]; } u;
    #pragma unroll
    for (int i = 0; i < 8; i++) u.h[i] = f2b(px[(size_t)i * S_TOT]);
    *(uint4*)((char*)xT + z * 512 + ((c16 ^ (z & 7)) << 4)) = u.q;
  }
  __syncthreads();

  const int proj = wave >> 3;            // 0=q (waves 0-7), 1=k (waves 8-15)
  const int rb = (wave & 7) * 32;        // row base within proj
  const float* bias = proj ? bk : bq;

  // ---- q,k GEMM: wave owns 32 rows x 96 cols (acc[2][6], proven shape)
  f32x4 acc[2][6];
  #pragma unroll
  for (int fr = 0; fr < 2; fr++){
    f32x4 iv;
    #pragma unroll
    for (int j = 0; j < 4; j++) iv[j] = bias[rb + fr * 16 + l4 * 4 + j];
    #pragma unroll
    for (int fc = 0; fc < 6; fc++) acc[fr][fc] = iv;
  }
  #pragma unroll
  for (int ck = 0; ck < 8; ck++){
    bf16x8 af[2], bfr[6];
    #pragma unroll
    for (int fr = 0; fr < 2; fr++){
      int row = wave * 32 + fr * 16 + l15;       // row within 512 (q|k)
      af[fr] = *(const bf16x8*)(wimg + ck * 16384 + row * 32 + l4 * 8);
    }
    #pragma unroll
    for (int fc = 0; fc < 6; fc++){
      int z = fc * 16 + l15;
      bfr[fc] = *(const bf16x8*)((char*)xT + z * 512 + (((ck * 4 + l4) ^ (l15 & 7)) << 4));
    }
    #pragma unroll
    for (int fr = 0; fr < 2; fr++)
      #pragma unroll
      for (int fc = 0; fc < 6; fc++)
        acc[fr][fc] = mfma16(af[fr], bfr[fc], acc[fr][fc]);
  }
  __syncthreads();   // ALL waves done reading xT; region reusable as qkz

  const int och = proj * 256 + rb + l4 * 4;          // + fr*16
  const int ca = l15 * 32 + l4 * 8;                  // q channels (rows 8-15 junk)
  const int cb = 256 + (l15 & 7) * 32 + l4 * 8;      // k channels (dup col>=8)

  // ======== half 0: column bx*2 (global z 0..47) ========
  #pragma unroll
  for (int fr = 0; fr < 2; fr++){
    int oc = och + fr * 16;
    #pragma unroll
    for (int fc = 0; fc < 3; fc++){
      int zl = fc * 16 + l15;
      ushort4 u;
      u.x = f2b(acc[fr][fc][0]); u.y = f2b(acc[fr][fc][1]);
      u.z = f2b(acc[fr][fc][2]); u.w = f2b(acc[fr][fc][3]);
      *(ushort4*)((char*)qkz + zl * 1024 + ((((oc >> 3) ^ zl) & 63) << 4)
                  + (oc & 7) * 2) = u;
    }
  }
  __syncthreads();
  {
    f32x4 sc = {0.f, 0.f, 0.f, 0.f};
    #pragma unroll
    for (int zi = 0; zi < 3; zi++){
      int zl = wave * 3 + zi;
      bf16x8 aq  = *(const bf16x8*)((char*)qkz + zl * 1024 + ((((ca >> 3) ^ zl) & 63) << 4));
      bf16x8 bk8 = *(const bf16x8*)((char*)qkz + zl * 1024 + ((((cb >> 3) ^ zl) & 63) << 4));
      sc = mfma16(aq, bk8, sc);
    }
    if (l4 < 2 && l15 < 8){
      #pragma unroll
      for (int j = 0; j < 4; j++)
        ps0[wave * 64 + (l4 * 4 + j) * 8 + l15] = sc[j];
    }
  }
  __syncthreads();

  // reduce col 0 (reads ps0) runs alongside half-1 epilogue (writes qkz)
  if (tid < 64){
    float s = 0.f;
    #pragma unroll
    for (int w = 0; w < 16; w++) s += ps0[w * 64 + tid];
    scores[(size_t)(b * 64 + tid) * NBX + bx * 2] = s * 0.17677669529663687f;
  }
  // ======== half 1: column bx*2+1 (global z 48..95) ========
  #pragma unroll
  for (int fr = 0; fr < 2; fr++){
    int oc = och + fr * 16;
    #pragma unroll
    for (int fc = 3; fc < 6; fc++){
      int zl = (fc - 3) * 16 + l15;
      ushort4 u;
      u.x = f2b(acc[fr][fc][0]); u.y = f2b(acc[fr][fc][1]);
      u.z = f2b(acc[fr][fc][2]); u.w = f2b(acc[fr][fc][3]);
      *(ushort4*)((char*)qkz + zl * 1024 + ((((oc >> 3) ^ zl) & 63) << 4)
                  + (oc & 7) * 2) = u;
    }
  }
  __syncthreads();
  {
    f32x4 sc = {0.f, 0.f, 0.f, 0.f};
    #pragma unroll
    for (int zi = 0; zi < 3; zi++){
      int zl = wave * 3 + zi;
      bf16x8 aq  = *(const bf16x8*)((char*)qkz + zl * 1024 + ((((ca >> 3) ^ zl) & 63) << 4));
      bf16x8 bk8 = *(const bf16x8*)((char*)qkz + zl * 1024 + ((((cb >> 3) ^ zl) & 63) << 4));
      sc = mfma16(aq, bk8, sc);
    }
    if (l4 < 2 && l15 < 8){
      #pragma unroll
      for (int j = 0; j < 4; j++)
        ps1[wave * 64 + (l4 * 4 + j) * 8 + l15] = sc[j];
    }
  }
  __syncthreads();
  if (tid < 64){
    float s = 0.f;
    #pragma unroll
    for (int w = 0; w < 16; w++) s += ps1[w * 64 + tid];
    scores[(size_t)(b * 64 + tid) * NBX + bx * 2 + 1] = s * 0.17677669529663687f;
  }
}

// ---------------- K2: softmax over y ------------------------------------------
__global__ __launch_bounds__(256) void k_softmax(
    const float* __restrict__ scores, float* __restrict__ attn)
{
  int row  = blockIdx.x * 4 + (threadIdx.x >> 6);
  int lane = threadIdx.x & 63;
  const float* src = scores + (size_t)row * 48;
  float v = (lane < 48) ? src[lane] : -1e30f;
  float m = v;
  #pragma unroll
  for (int off = 32; off; off >>= 1) m = fmaxf(m, __shfl_xor(m, off));
  float e = (lane < 48) ? __expf(v - m) : 0.f;
  float s = e;
  #pragma unroll
  for (int off = 32; off; off >>= 1) s += __shfl_xor(s, off);
  if (lane < 48) attn[(size_t)row * 48 + lane] = e / s;
}

// ---------------- K3: 96-spatial (y-pair): v proj + attn*v + wo GEMM ---------
// R13 body; ONLY change: final out stores are NON-TEMPORAL (keep x in L3).
#define K3_LDS 49664
__global__ __launch_bounds__(512, 4) void k_out(
    const float* __restrict__ x, const u16* __restrict__ wvimg,
    const u16* __restrict__ woimg, const float* __restrict__ bv,
    const float* __restrict__ bo, const float* __restrict__ attn,
    float* __restrict__ out)
{
  extern __shared__ char lds[];
  u16* xT = (u16*)lds;
  u16* vl = (u16*)lds;
  u16* oT = (u16*)lds;
  float* atl = (float*)(lds + 49152);

  const int tid  = threadIdx.x;
  const int wave = tid >> 6, lane = tid & 63;
  const int l15 = lane & 15, l4 = lane >> 4;
  const int bx = blockIdx.x, b = blockIdx.y;   // bx: 0..1151 (y-pair)
  const int s0 = bx * 96;
  const float* xb = x + (size_t)b * 256 * S_TOT;

  if (tid < 128)
    atl[tid] = attn[(size_t)(b * 64 + (tid & 63)) * NBX + bx * 2 + (tid >> 6)];

  // stage x -> xT [96 z][256 ch] (R8 scalar-granule form)
  #pragma unroll
  for (int it = 0; it < 6; it++){
    int e = it * 512 + tid;
    int z = e % 96, c16 = e / 96;
    const float* px = xb + (size_t)(c16 * 8) * S_TOT + s0 + z;
    union { uint4 q; u16 h[8]; } u;
    #pragma unroll
    for (int i = 0; i < 8; i++) u.h[i] = f2b(px[(size_t)i * S_TOT]);
    *(uint4*)((char*)xT + z * 512 + ((c16 ^ (z & 7)) << 4)) = u.q;
  }
  __syncthreads();

  // ---- v GEMM: wave owns channels wave*32..+31, 96 spatial cols
  f32x4 vac[2][6];
  #pragma unroll
  for (int fr = 0; fr < 2; fr++){
    f32x4 iv;
    #pragma unroll
    for (int j = 0; j < 4; j++) iv[j] = bv[wave * 32 + fr * 16 + l4 * 4 + j];
    #pragma unroll
    for (int fc = 0; fc < 6; fc++) vac[fr][fc] = iv;
  }
  #pragma unroll
  for (int ck = 0; ck < 8; ck++){
    bf16x8 af[2], bfr[6];
    #pragma unroll
    for (int fr = 0; fr < 2; fr++){
      int row = wave * 32 + fr * 16 + l15;
      af[fr] = *(const bf16x8*)(wvimg + ck * 8192 + row * 32 + l4 * 8);
    }
    #pragma unroll
    for (int fc = 0; fc < 6; fc++){
      int z = fc * 16 + l15;
      bfr[fc] = *(const bf16x8*)((char*)xT + z * 512 + (((ck * 4 + l4) ^ (l15 & 7)) << 4));
    }
    #pragma unroll
    for (int fr = 0; fr < 2; fr++)
      #pragma unroll
      for (int fc = 0; fc < 6; fc++)
        vac[fr][fc] = mfma16(af[fr], bfr[fc], vac[fr][fc]);
  }
  __syncthreads();

  // ---- v epilogue -> vl (overwrites xT)
  #pragma unroll
  for (int fr = 0; fr < 2; fr++){
    int o0 = wave * 32 + fr * 16 + l4 * 4;
    #pragma unroll
    for (int fc = 0; fc < 6; fc++){
      int z = fc * 16 + l15;
      ushort4 u;
      u.x = f2b(vac[fr][fc][0]); u.y = f2b(vac[fr][fc][1]);
      u.z = f2b(vac[fr][fc][2]); u.w = f2b(vac[fr][fc][3]);
      *(ushort4*)((char*)vl + z * 512 + (((o0 >> 3) ^ (z & 7)) << 4) + (o0 & 7) * 2) = u;
    }
  }
  __syncthreads();

  // ---- einsum IN PLACE: it covers z rows [it*16, it*16+16)
  #pragma unroll
  for (int it = 0; it < 6; it++){
    int e = it * 512 + tid;
    int c16 = e & 31, z = e >> 5;
    int r = c16 & 3, hn = c16 >> 2;
    const float* at = atl + ((z >= 48) ? 64 : 0);
    float a[8] = {0,0,0,0,0,0,0,0};
    #pragma unroll
    for (int m = 0; m < 8; m++){
      union { uint4 q; u16 h[8]; } v8;
      v8.q = *(const uint4*)((char*)vl + z * 512 + (((m * 4 + r) ^ (z & 7)) << 4));
      float am = at[hn * 8 + m];
      #pragma unroll
      for (int i = 0; i < 8; i++) a[i] = fmaf(am, b2f(v8.h[i]), a[i]);
    }
    union { uint4 q; u16 h[8]; } pk;
    #pragma unroll
    for (int i = 0; i < 8; i++) pk.h[i] = f2b(a[i]);
    __syncthreads();
    *(uint4*)((char*)oT + z * 512 + ((c16 ^ (z & 7)) << 4)) = pk.q;
  }
  __syncthreads();

  // ---- wo GEMM (reads oT)
  f32x4 oac[2][6];
  #pragma unroll
  for (int fr = 0; fr < 2; fr++){
    f32x4 iv;
    #pragma unroll
    for (int j = 0; j < 4; j++) iv[j] = bo[wave * 32 + fr * 16 + l4 * 4 + j];
    #pragma unroll
    for (int fc = 0; fc < 6; fc++) oac[fr][fc] = iv;
  }
  #pragma unroll
  for (int ck = 0; ck < 8; ck++){
    bf16x8 af[2], bfr[6];
    #pragma unroll
    for (int fr = 0; fr < 2; fr++){
      int row = wave * 32 + fr * 16 + l15;
      af[fr] = *(const bf16x8*)(woimg + ck * 8192 + row * 32 + l4 * 8);
    }
    #pragma unroll
    for (int fc = 0; fc < 6; fc++){
      int z = fc * 16 + l15;
      bfr[fc] = *(const bf16x8*)((char*)oT + z * 512 + (((ck * 4 + l4) ^ (l15 & 7)) << 4));
    }
    #pragma unroll
    for (int fr = 0; fr < 2; fr++)
      #pragma unroll
      for (int fc = 0; fc < 6; fc++)
        oac[fr][fc] = mfma16(af[fr], bfr[fc], oac[fr][fc]);
  }

  // ---- store fp32: 384 B contiguous per channel, NON-TEMPORAL (bypass L3
  //      so x stays cache-resident; out is write-once, never re-read)
  #pragma unroll
  for (int fr = 0; fr < 2; fr++)
    #pragma unroll
    for (int fc = 0; fc < 6; fc++)
      #pragma unroll
      for (int j = 0; j < 4; j++){
        int o = wave * 32 + fr * 16 + l4 * 4 + j;
        int z = fc * 16 + l15;
        __builtin_nontemporal_store(oac[fr][fc][j],
            &out[(size_t)(b * 256 + o) * S_TOT + s0 + z]);
      }
}

// ---------------- launch ------------------------------------------------------
extern "C" void kernel_launch(void* const* d_in, const int* in_sizes, int n_in,
                              void* d_out, int out_size, void* d_ws, size_t ws_size,
                              hipStream_t stream) {
  (void)in_sizes; (void)n_in; (void)out_size; (void)ws_size;
  const float* x  = (const float*)d_in[0];
  const float* wq = (const float*)d_in[1];
  const float* bq = (const float*)d_in[2];
  const float* wk = (const float*)d_in[3];
  const float* bk = (const float*)d_in[4];
  const float* wv = (const float*)d_in[5];
  const float* bv = (const float*)d_in[6];
  const float* wo = (const float*)d_in[7];
  const float* bo = (const float*)d_in[8];
  float* out = (float*)d_out;

  char* ws = (char*)d_ws;
  u16*  wimg   = (u16*)ws;                    // 262144 u16 = 524288 B
  u16*  wvimg  = wimg + 131072;
  u16*  woimg  = wimg + 196608;
  float* scores = (float*)(ws + 524288);      // 128*2304*4 = 1179648 B
  float* attn   = (float*)(ws + 1703936);     // 1179648 B (end ~2.9 MB)

  k_prep<<<1024, 256, 0, stream>>>(wq, wk, wv, wo, wimg);
  k_qk_scores<<<dim3(1152, 2), 1024, K1_LDS, stream>>>(x, wimg, bq, bk, scores);
  k_softmax<<<1536, 256, 0, stream>>>(scores, attn);
  k_out<<<dim3(1152, 2), 512, K3_LDS, stream>>>(x, wvimg, woimg, bv, bo, attn, out);
}